// Round 8
// baseline (307.461 us; speedup 1.0000x reference)
//
#include <hip/hip_runtime.h>
#include <cstddef>

// Problem constants (from reference)
#define NN 20000      // nodes
#define NE 320000     // edges
#define DIM 256       // model dim
#define NHEAD 8
#define DHEAD 32      // DK == DV == 32
#define NLAYER 2
#define HUS 1024

typedef __bf16 bf16x8 __attribute__((ext_vector_type(8)));
typedef __bf16 bf16x4 __attribute__((ext_vector_type(4)));
typedef float  f32x4  __attribute__((ext_vector_type(4)));
typedef float  f32x2  __attribute__((ext_vector_type(2)));

// async global->LDS, 16B per lane; LDS dest must be wave-uniform base + lane*16
#define GLDS16(g, l) __builtin_amdgcn_global_load_lds(                        \
    (const __attribute__((address_space(1))) void*)(g),                       \
    (__attribute__((address_space(3))) void*)(l), 16, 0, 0)

// pack 4 fp32 -> 4 fp8 e4m3 (OCP on gfx950) in one uint
static __device__ inline unsigned pk_fp8x4(f32x4 x) {
  int v = 0;
  v = __builtin_amdgcn_cvt_pk_fp8_f32(x[0], x[1], v, false);
  v = __builtin_amdgcn_cvt_pk_fp8_f32(x[2], x[3], v, true);
  return (unsigned)v;
}

// ---------------------------------------------------------------------------
// bf16 MFMA GEMM: C[M,N] = A[M,K] @ Bt[N,K]^T  (A, Bt bf16 row-major)
// BM = BMT (128 or 64), BN=128, 256 threads = 4 waves 2x2.
// DEPTH-2 PIPELINE AT 2 BUFFERS (this round): buffer p is free for
// overwrite once all waves' ds_reads of step s complete (not end-of-step).
// Per step:
//   ds_read frags from buf p
//   lgkmcnt(0); s_barrier                  (read-release: p reusable)
//   issue GLDS stage s+2 -> buf p          (2 stages now in flight)
//   MFMA (frag regs already loaded)
//   s_waitcnt vmcnt(LOADS); s_barrier      (stage s+1 landed; s+2 flying)
// Same 32 KB LDS -> 5 blocks/CU (round-3's 3-stage/48KB lost occupancy);
// each stage gets ~2 steps of latency cover; vmcnt never drains to 0
// mid-loop (T4). Wave-uniform load counts REQUIRED for counted vmcnt:
// edge-block A rows are clamped (min(row,M-1)), stores still masked gr<M.
// LDS swizzle (T2, 64B rows): (row, 16B-chunk) stored at chunk^((row>>1)&3);
// global source pre-swizzled (linear GLDS dest), read back with
// ko = (quad ^ ((col15>>1)&3))*8 -> conflict-free ds_read_b128.
// XCD swizzle: grid (8, ceil(mtiles/8)*ntiles); m = bx + 8*(by/ntiles).
// outmode: 0 = fp32, 1 = bf16, 2 = qkv-mixed (row = 1024B: 256 bf16 q at
// byte 0, 512 fp8 kv at byte 512; tiles bn<256 -> bf16, bn>=256 -> fp8).
// C/D layout: col = lane&15, row = quad*4 + reg.
// ---------------------------------------------------------------------------
template <int TAG, int BMT>
__global__ __launch_bounds__(256) void gemm_bf16_t(
    const __bf16* __restrict__ A, int lda,
    const __bf16* __restrict__ Bt, int ldb,
    void* __restrict__ C, int ldc,
    const float* __restrict__ bias,
    int M, int N, int K, int relu, int outmode,
    int mtiles, int ntiles)
{
  constexpr int MT = BMT / 32;            // m-tiles per wave
  constexpr int BOFF = BMT * 32;          // Bs offset (elems) within buffer
  constexpr int LOADS = (BMT == 128) ? 4 : 3;  // GLDS per thread per stage
  const int mblk = blockIdx.x + 8 * (blockIdx.y / ntiles);
  const int nblk = blockIdx.y % ntiles;
  if (mblk >= mtiles) return;             // uniform early-out (idle pad blocks)
  __shared__ __align__(16) __bf16 smem[2][256 * 32];  // 32 KB total
  const int tid  = threadIdx.x;
  const int wave = tid >> 6;
  const int lane = tid & 63;
  const int bm = mblk * BMT;
  const int bn = nblk * 128;
  const int wm = (wave >> 1) * (BMT / 2);
  const int wn = (wave & 1) * 64;
  const int quad  = lane >> 4;
  const int col15 = lane & 15;

  // A staging per 32-K step: BMT*4 chunks of 16B; source chunk pre-swizzled.
  // Rows CLAMPED to M-1 (not predicated) so every wave issues exactly LOADS
  // GLDS per stage -> counted vmcnt is wave-uniform. OOB rows masked at store.
  const int swsrc = ((tid & 3) ^ ((tid >> 3) & 3)) * 8;   // elems
  const int ar1r = min(bm + (tid >> 2), M - 1);
  const __bf16* ag1 = A + (size_t)ar1r * lda + swsrc;
  const int ar2r = min(bm + ((tid + 256) >> 2), M - 1);
  const __bf16* ag2 = A + (size_t)ar2r * lda + swsrc; // (tid+256)>>3 ≡ tid>>3 (mod 4)

  // stage one 32-K step at global K-offset k into LDS buffer p
  auto stage_step = [&](int k, int p) {
    GLDS16(ag1 + k, &smem[p][tid * 8]);
    if (BMT == 128) {
      GLDS16(ag2 + k, &smem[p][(tid + 256) * 8]);
    }
#pragma unroll
    for (int i = 0; i < 2; ++i) {   // B: 512 chunks per step
      int c = tid + i * 256;
      GLDS16(Bt + (size_t)(bn + (c >> 2)) * ldb
                 + (((c & 3) ^ ((c >> 3) & 3)) * 8) + k,
             &smem[p][BOFF + c * 8]);
    }
  };

  f32x4 acc[MT][4];
#pragma unroll
  for (int i = 0; i < MT; ++i)
#pragma unroll
    for (int j = 0; j < 4; ++j) acc[i][j] = (f32x4){0.f, 0.f, 0.f, 0.f};

  const int nsteps = K >> 5;              // >= 8 for all shapes here
  stage_step(0, 0);
  stage_step(32, 1);
  asm volatile("s_waitcnt vmcnt(%0)" :: "i"(LOADS) : "memory");  // stage 0 in
  __builtin_amdgcn_sched_barrier(0);
  __builtin_amdgcn_s_barrier();
  __builtin_amdgcn_sched_barrier(0);

  int p = 0;
  const int ko = (quad ^ ((col15 >> 1) & 3)) * 8;  // swizzled chunk read
  for (int s = 0; s < nsteps; ++s) {
    bf16x8 af[MT], bfr[4];
#pragma unroll
    for (int mt = 0; mt < MT; ++mt)
      af[mt] = *(const bf16x8*)(&smem[p][(wm + mt * 16 + col15) * 32 + ko]);
#pragma unroll
    for (int nt = 0; nt < 4; ++nt)
      bfr[nt] = *(const bf16x8*)(
          &smem[p][BOFF + (wn + nt * 16 + col15) * 32 + ko]);
    asm volatile("s_waitcnt lgkmcnt(0)" ::: "memory");   // my reads of p done
    __builtin_amdgcn_sched_barrier(0);
    __builtin_amdgcn_s_barrier();                        // ALL reads of p done
    __builtin_amdgcn_sched_barrier(0);
    if (s + 2 < nsteps) stage_step((s + 2) * 32, p);     // overwrite p (safe)
#pragma unroll
    for (int mt = 0; mt < MT; ++mt)
#pragma unroll
      for (int nt = 0; nt < 4; ++nt)
        acc[mt][nt] = __builtin_amdgcn_mfma_f32_16x16x32_bf16(
            af[mt], bfr[nt], acc[mt][nt], 0, 0, 0);
    if (s + 1 < nsteps) {
      if (s + 2 < nsteps)   // steady: stage s+1 done, s+2 stays in flight
        asm volatile("s_waitcnt vmcnt(%0)" :: "i"(LOADS) : "memory");
      else                  // tail: drain all
        asm volatile("s_waitcnt vmcnt(0)" ::: "memory");
      __builtin_amdgcn_sched_barrier(0);
      __builtin_amdgcn_s_barrier();
      __builtin_amdgcn_sched_barrier(0);
    }
    p ^= 1;
  }

  // ---- LDS-restaged epilogue ----
  float bv[4];
#pragma unroll
  for (int nt = 0; nt < 4; ++nt)
    bv[nt] = bias ? bias[bn + wn + nt * 16 + col15] : 0.f;

  float* stg = ((float*)&smem[0][0]) + wave * 2048;  // 8 KB/wave

#pragma unroll
  for (int mt = 0; mt < MT; ++mt) {
    __syncthreads();  // uniform; protects smem reuse across quarters
#pragma unroll
    for (int nt = 0; nt < 4; ++nt)
#pragma unroll
      for (int r = 0; r < 4; ++r) {
        float o = acc[mt][nt][r] + bv[nt];
        if (relu) o = fmaxf(o, 0.f);
        stg[(quad * 4 + r) * 68 + nt * 16 + col15] = o;
      }
    const int rbase = bm + wm + mt * 16;
    if (outmode == 0) {                       // fp32 out
      float* Cf = (float*)C;
#pragma unroll
      for (int it = 0; it < 4; ++it) {
        int t = it * 64 + lane;
        int row = t >> 4, cg = t & 15;
        int gr = rbase + row;
        if (gr < M) {
          f32x4 x = *(const f32x4*)(stg + row * 68 + cg * 4);
          *(f32x4*)(Cf + (size_t)gr * ldc + bn + wn + cg * 4) = x;
        }
      }
    } else if (outmode == 1 || bn < 256) {    // bf16 out (ldc in bf16 units)
      __bf16* Cb = (__bf16*)C;
#pragma unroll
      for (int it = 0; it < 2; ++it) {
        int t = it * 64 + lane;
        int row = t >> 3, cg = t & 7;
        int gr = rbase + row;
        if (gr < M) {
          f32x4 x = *(const f32x4*)(stg + row * 68 + cg * 8);
          f32x4 y = *(const f32x4*)(stg + row * 68 + cg * 8 + 4);
          __bf16 o8[8] = {(__bf16)x[0], (__bf16)x[1], (__bf16)x[2], (__bf16)x[3],
                          (__bf16)y[0], (__bf16)y[1], (__bf16)y[2], (__bf16)y[3]};
          *(uint4*)(Cb + (size_t)gr * ldc + bn + wn + cg * 8) = *(uint4*)o8;
        }
      }
    } else {                                   // fp8 kv region of qkv row
      unsigned char* C8 = (unsigned char*)C;
      int row = lane >> 2, cg = lane & 3;      // 16 rows x 4 groups of 16 cols
      int gr = rbase + row;
      if (gr < M) {
        uint4 o;
        o.x = pk_fp8x4(*(const f32x4*)(stg + row * 68 + cg * 16 + 0));
        o.y = pk_fp8x4(*(const f32x4*)(stg + row * 68 + cg * 16 + 4));
        o.z = pk_fp8x4(*(const f32x4*)(stg + row * 68 + cg * 16 + 8));
        o.w = pk_fp8x4(*(const f32x4*)(stg + row * 68 + cg * 16 + 12));
        *(uint4*)(C8 + (size_t)gr * 1024 + 512 + (bn - 256) + wn + cg * 16) = o;
      }
    }
  }
}

// ---------------------------------------------------------------------------
// Fused Wo-GEMM + residual + LayerNorm, LDS-restaged output.
// Same depth-2 2-buffer pipeline as gemm_bf16_t. Per-wave GLDS counts
// differ (waves 0-1: A+4B = 5, waves 2-3: 4B) -> wave-uniform branch picks
// the matching vmcnt immediate. M = 20000 divisible by 32: no edge blocks.
// Residual source (hres, fp32) decoupled from fp32 output (hout):
// layer 0 reads h_in directly; layer 1 passes hout=nullptr (dead store).
// ---------------------------------------------------------------------------
__global__ __launch_bounds__(256) void gemm_wo_ln(
    const __bf16* __restrict__ A,   // agg bf16 [M][256]
    const __bf16* __restrict__ Bt,  // wot [256][256]
    const float* __restrict__ hres, // fp32 residual in
    float* __restrict__ hout,       // fp32 LN out (may be null)
    __bf16* __restrict__ hb,        // bf16 LN out
    const float* __restrict__ g, const float* __restrict__ bb)
{
  __shared__ __align__(16) __bf16 smem[2][288 * 32];
  __shared__ float red_s[32][2], red_q[32][2];
  const int tid  = threadIdx.x;
  const int wave = tid >> 6;
  const int lane = tid & 63;
  const int quad  = lane >> 4;
  const int col15 = lane & 15;
  const int bm = blockIdx.x * 32;
  const int wm = (wave >> 1) * 16;
  const int wn = (wave & 1) * 128;
  const int ch = wave & 1;

  const int ac   = tid & 127;
  const int arow = ac >> 2;
  const int aoff = ((ac & 3) ^ ((ac >> 3) & 3)) * 8;   // pre-swizzled source
  const __bf16* agp = A + (size_t)(bm + arow) * 256 + aoff;

  // stage one 32-K step at global K-offset k into LDS buffer p:
  // A: 128 chunks (threads 0..127 = waves 0,1), B: 1024 chunks (4/thread)
  auto stage_step = [&](int k, int p) {
    if (tid < 128) GLDS16(agp + k, &smem[p][ac * 8]);
#pragma unroll
    for (int i = 0; i < 4; ++i) {
      int c = tid + i * 256;
      GLDS16(Bt + (size_t)(c >> 2) * 256
                 + (((c & 3) ^ ((c >> 3) & 3)) * 8) + k,
             &smem[p][1024 + c * 8]);
    }
  };
  // per-wave counted vmcnt (wave-uniform branch; waves 0-1 issue 5, 2-3 issue 4)
  auto wait_stage = [&]() {
    if (tid < 128) asm volatile("s_waitcnt vmcnt(5)" ::: "memory");
    else           asm volatile("s_waitcnt vmcnt(4)" ::: "memory");
  };

  f32x4 acc[8];
#pragma unroll
  for (int j = 0; j < 8; ++j) acc[j] = (f32x4){0.f, 0.f, 0.f, 0.f};

  stage_step(0, 0);
  stage_step(32, 1);
  wait_stage();                              // stage 0 landed
  __builtin_amdgcn_sched_barrier(0);
  __builtin_amdgcn_s_barrier();
  __builtin_amdgcn_sched_barrier(0);

  int p = 0;
  const int ko = (quad ^ ((col15 >> 1) & 3)) * 8;  // swizzled chunk read
  for (int s = 0; s < 8; ++s) {                    // 256/32 steps
    bf16x8 af = *(const bf16x8*)(&smem[p][(wm + col15) * 32 + ko]);
    bf16x8 bfr[8];
#pragma unroll
    for (int nt = 0; nt < 8; ++nt)
      bfr[nt] = *(const bf16x8*)(
          &smem[p][1024 + (wn + nt * 16 + col15) * 32 + ko]);
    asm volatile("s_waitcnt lgkmcnt(0)" ::: "memory");
    __builtin_amdgcn_sched_barrier(0);
    __builtin_amdgcn_s_barrier();                  // all reads of p done
    __builtin_amdgcn_sched_barrier(0);
    if (s + 2 < 8) stage_step((s + 2) * 32, p);    // overwrite p (safe)
#pragma unroll
    for (int nt = 0; nt < 8; ++nt)
      acc[nt] = __builtin_amdgcn_mfma_f32_16x16x32_bf16(af, bfr[nt], acc[nt],
                                                        0, 0, 0);
    if (s + 1 < 8) {
      if (s + 2 < 8) wait_stage();
      else           asm volatile("s_waitcnt vmcnt(0)" ::: "memory");
      __builtin_amdgcn_sched_barrier(0);
      __builtin_amdgcn_s_barrier();
      __builtin_amdgcn_sched_barrier(0);
    }
    p ^= 1;
  }

#pragma unroll
  for (int r = 0; r < 4; ++r) {
    const int lr = wm + quad * 4 + r;
    const int gr = bm + lr;
    float s = 0.f, q = 0.f;
#pragma unroll
    for (int nt = 0; nt < 8; ++nt) {
      int gc = wn + nt * 16 + col15;
      float x = acc[nt][r] + hres[(size_t)gr * 256 + gc];
      acc[nt][r] = x;
      s += x; q += x * x;
    }
    s += __shfl_xor(s, 1); q += __shfl_xor(q, 1);
    s += __shfl_xor(s, 2); q += __shfl_xor(q, 2);
    s += __shfl_xor(s, 4); q += __shfl_xor(q, 4);
    s += __shfl_xor(s, 8); q += __shfl_xor(q, 8);
    if (col15 == 0) { red_s[lr][ch] = s; red_q[lr][ch] = q; }
  }
  __syncthreads();

  float* stg = (float*)&smem[0][0];
#pragma unroll
  for (int r = 0; r < 4; ++r) {
    const int lr = wm + quad * 4 + r;
    float s = red_s[lr][0] + red_s[lr][1];
    float q = red_q[lr][0] + red_q[lr][1];
    float mu  = s * (1.f / 256);
    float var = q * (1.f / 256) - mu * mu;
    float inv = rsqrtf(var + 1e-5f);
#pragma unroll
    for (int nt = 0; nt < 8; ++nt) {
      int gc = wn + nt * 16 + col15;
      stg[lr * 260 + gc] = (acc[nt][r] - mu) * inv * g[gc] + bb[gc];
    }
  }
  __syncthreads();

  if (hout) {
#pragma unroll
    for (int it = 0; it < 8; ++it) {
      int t = it * 256 + tid;
      int row = t >> 6, cg = t & 63;
      f32x4 x = *(const f32x4*)(stg + row * 260 + cg * 4);
      *(f32x4*)(hout + (size_t)(bm + row) * 256 + cg * 4) = x;
    }
  }
#pragma unroll
  for (int it = 0; it < 4; ++it) {
    int t = it * 256 + tid;
    int row = t >> 5, cg = t & 31;
    f32x4 x = *(const f32x4*)(stg + row * 260 + cg * 8);
    f32x4 y = *(const f32x4*)(stg + row * 260 + cg * 8 + 4);
    __bf16 o8[8] = {(__bf16)x[0], (__bf16)x[1], (__bf16)x[2], (__bf16)x[3],
                    (__bf16)y[0], (__bf16)y[1], (__bf16)y[2], (__bf16)y[3]};
    *(uint4*)(hb + (size_t)(bm + row) * 256 + cg * 8) = *(uint4*)o8;
  }
}

// ---------------------------------------------------------------------------
// PREP mega-kernel: transposes | h-init (bf16 only; fp32 copy eliminated —
// layer-1 residual reads h_in directly) | histogram.
// ---------------------------------------------------------------------------
__global__ __launch_bounds__(256) void prep_kernel(
    const float* __restrict__ Wq, const float* __restrict__ Wk,
    const float* __restrict__ Wv, const float* __restrict__ Wo,
    const float* __restrict__ w1, const float* __restrict__ w2,
    __bf16* __restrict__ wqkvt, __bf16* __restrict__ wot,
    __bf16* __restrict__ w1t, __bf16* __restrict__ w2t,
    const float* __restrict__ h_in,
    __bf16* __restrict__ hb,
    const int* __restrict__ dst, int* __restrict__ cnt)
{
  __shared__ float t[32][33];
  const int b = blockIdx.x;
  if (b >= 3524) {               // ---- histogram ----
    int e = (b - 3524) * 256 + threadIdx.x;
    if (e < NE) atomicAdd(&cnt[dst[e]], 1);
    return;
  }
  if (b >= 1024) {               // ---- h init (bf16 mirror only) ----
    int i = ((b - 1024) * 256 + threadIdx.x) * 8;
    if (i >= NN * DIM) return;
    float4 a = *(const float4*)(h_in + i);
    float4 c = *(const float4*)(h_in + i + 4);
    __bf16 o[8] = {(__bf16)a.x, (__bf16)a.y, (__bf16)a.z, (__bf16)a.w,
                   (__bf16)c.x, (__bf16)c.y, (__bf16)c.z, (__bf16)c.w};
    *(uint4*)(hb + i) = *(uint4*)o;
    return;
  }
  // ---- weight transposes ----
  const float* src;
  __bf16* dstp;
  int N, Kd, bk, bn, mode = 0;  // 0: identity, 1: k-perm, 2: v-perm
  if (b < 512) {
    int m = b >> 6, tt = b & 63;
    bk = (tt & 7) * 32; bn = (tt >> 3) * 32;
    N = 256; Kd = 256;
    int l = m & 1, w = m >> 1;  // w: 0=Wq 1=Wk 2=Wv 3=Wo
    const float* Ws[4] = {Wq, Wk, Wv, Wo};
    src = Ws[w] + (size_t)l * 65536;
    if (w == 3) dstp = wot + (size_t)l * 65536;
    else { dstp = wqkvt + (size_t)l * 196608; mode = (w == 0) ? 0 : w; }
  } else if (b < 768) {
    int tt = b - 512;
    bk = (tt & 7) * 32; bn = (tt >> 3) * 32;
    N = 1024; Kd = 256; src = w1; dstp = w1t;
  } else {
    int tt = b - 768;
    bk = (tt >> 3) * 32; bn = (tt & 7) * 32;
    N = 256; Kd = 1024; src = w2; dstp = w2t;
  }
  const int tx = threadIdx.x & 31, ty = threadIdx.x >> 5;
#pragma unroll
  for (int i = 0; i < 32; i += 8)
    t[ty + i][tx] = src[(size_t)(bk + ty + i) * N + bn + tx];
  __syncthreads();
#pragma unroll
  for (int i = 0; i < 32; i += 8) {
    int n = bn + ty + i;
    int r = (mode == 0) ? n
          : 256 + ((n >> 2) * 8) + (n & 3) + (mode == 2 ? 4 : 0);
    dstp[(size_t)r * Kd + bk + tx] = (__bf16)t[tx][ty + i];
  }
}

// ---------------------------------------------------------------------------
// CSR build: shfl-based scan (2 barriers) + scatter.
// Re-zeros cnt for cursor reuse; stores SRC id per CSR slot.
// ---------------------------------------------------------------------------
__global__ __launch_bounds__(1024) void scan_kernel(
    int* __restrict__ cnt, int* __restrict__ rowstart)
{
  __shared__ int wsum[16];
  const int t = threadIdx.x;
  const int lane = t & 63, w = t >> 6;
  const int CHUNK = (NN + 1023) / 1024;  // 20
  const int base = t * CHUNK;
  int loc[CHUNK];
  int s = 0;
#pragma unroll
  for (int i = 0; i < CHUNK; ++i) {
    int idx = base + i;
    loc[i] = (idx < NN) ? cnt[idx] : 0;
    s += loc[i];
  }
  // wave-inclusive scan of per-thread sums
  int ps = s;
#pragma unroll
  for (int off = 1; off < 64; off <<= 1) {
    int v = __shfl_up(ps, off);
    if (lane >= off) ps += v;
  }
  if (lane == 63) wsum[w] = ps;
  __syncthreads();
  if (t < 16) {
    int v = wsum[t];
    int pv = v;
#pragma unroll
    for (int off = 1; off < 16; off <<= 1) {
      int u = __shfl_up(pv, off);
      if (t >= off) pv += u;
    }
    if (t == 15) rowstart[NN] = pv;   // total
    wsum[t] = pv - v;                 // exclusive wave prefix
  }
  __syncthreads();
  int run = wsum[w] + (ps - s);       // exclusive prefix for this thread
#pragma unroll
  for (int i = 0; i < CHUNK; ++i) {
    int idx = base + i;
    if (idx < NN) {
      rowstart[idx] = run;
      run += loc[i];
      cnt[idx] = 0;
    }
  }
}

__global__ __launch_bounds__(256) void scatter_kernel(
    const int* __restrict__ src, const int* __restrict__ dst,
    const int* __restrict__ rowstart,
    int* __restrict__ cursor, int* __restrict__ csrc, int E)
{
  int e = blockIdx.x * blockDim.x + threadIdx.x;
  if (e >= E) return;
  int d = dst[e];
  int pos = atomicAdd(&cursor[d], 1);
  csrc[rowstart[d] + pos] = src[e];
}

// ---------------------------------------------------------------------------
// Fused per-node attention, split-wave + depth-4 pipeline: one wave per dst
// node, two 32-lane halves each processing alternate edges with FOUR gathers
// in flight (p0..p3) -> 8 outstanding 512B gathers per wave (latency-bound
// regime: throughput ~ outstanding/latency).
// qkv rows 1024 B: q bf16 (bytes 0..511), kv fp8 e4m3 (512..1023).
// ---------------------------------------------------------------------------
__global__ __launch_bounds__(256) void node_attn(
    const unsigned char* __restrict__ qkv,
    const int* __restrict__ rowstart, const int* __restrict__ csrc,
    __bf16* __restrict__ agg)
{
  const int wave = threadIdx.x >> 6;
  const int lane = threadIdx.x & 63;
  const int hw   = lane >> 5;
  const int ln32 = lane & 31;
  const int d = blockIdx.x * 4 + wave;
  if (d >= NN) return;
  const int beg = rowstart[d], end = rowstart[d + 1];

  float qf[8];
  {
    bf16x8 q8 = *(const bf16x8*)(qkv + (size_t)d * 1024 + ln32 * 16);
#pragma unroll
    for (int j = 0; j < 8; ++j) qf[j] = (float)q8[j];
  }
  const float scale = 0.17677669529663687f;  // 1/sqrt(32)
  float z = 0.f;
  float ac[8];
#pragma unroll
  for (int j = 0; j < 8; ++j) ac[j] = 0.f;

  for (int c = beg; c < end; c += 64) {
    const int n = min(64, end - c);
    const int myi = c + lane;
    const int s_l = (myi < end) ? csrc[myi] : 0;   // coalesced batch load

    uint4 p0 = make_uint4(0u, 0u, 0u, 0u);
    uint4 p1 = make_uint4(0u, 0u, 0u, 0u);
    uint4 p2 = make_uint4(0u, 0u, 0u, 0u);
    uint4 p3 = make_uint4(0u, 0u, 0u, 0u);
    if (hw < n) {
      int s = __shfl(s_l, hw);
      p0 = *(const uint4*)(qkv + (size_t)s * 1024 + 512 + ln32 * 16);
    }
    if (hw + 2 < n) {
      int s = __shfl(s_l, hw + 2);
      p1 = *(const uint4*)(qkv + (size_t)s * 1024 + 512 + ln32 * 16);
    }
    if (hw + 4 < n) {
      int s = __shfl(s_l, hw + 4);
      p2 = *(const uint4*)(qkv + (size_t)s * 1024 + 512 + ln32 * 16);
    }
    if (hw + 6 < n) {
      int s = __shfl(s_l, hw + 6);
      p3 = *(const uint4*)(qkv + (size_t)s * 1024 + 512 + ln32 * 16);
    }
    for (int i = hw; i < n; i += 2) {
      uint4 kv = p0;
      p0 = p1; p1 = p2; p2 = p3;           // compile-time register shift
      if (i + 8 < n) {                     // refill the 4-deep pipe
        int sn = __shfl(s_l, i + 8);
        p3 = *(const uint4*)(qkv + (size_t)sn * 1024 + 512 + ln32 * 16);
      }
      f32x2 k01 = __builtin_amdgcn_cvt_pk_f32_fp8(kv.x, false);
      f32x2 k23 = __builtin_amdgcn_cvt_pk_f32_fp8(kv.x, true);
      f32x2 k45 = __builtin_amdgcn_cvt_pk_f32_fp8(kv.z, false);
      f32x2 k67 = __builtin_amdgcn_cvt_pk_f32_fp8(kv.z, true);
      float p = qf[0] * k01[0] + qf[1] * k01[1] + qf[2] * k23[0] +
                qf[3] * k23[1] + qf[4] * k45[0] + qf[5] * k45[1] +
                qf[6] * k67[0] + qf[7] * k67[1];
      p += __shfl_xor(p, 1);
      p += __shfl_xor(p, 2);
      float a = __expf(p * scale);
      z += a;
      f32x2 v01 = __builtin_amdgcn_cvt_pk_f32_fp8(kv.y, false);
      f32x2 v23 = __builtin_amdgcn_cvt_pk_f32_fp8(kv.y, true);
      f32x2 v45 = __builtin_amdgcn_cvt_pk_f32_fp8(kv.w, false);
      f32x2 v67 = __builtin_amdgcn_cvt_pk_f32_fp8(kv.w, true);
      ac[0] += a * v01[0]; ac[1] += a * v01[1];
      ac[2] += a * v23[0]; ac[3] += a * v23[1];
      ac[4] += a * v45[0]; ac[5] += a * v45[1];
      ac[6] += a * v67[0]; ac[7] += a * v67[1];
    }
  }
  // combine halves
  z += __shfl_xor(z, 32);
#pragma unroll
  for (int j = 0; j < 8; ++j) ac[j] += __shfl_xor(ac[j], 32);
  const float inv = 1.f / (z + 1e-9f);
  if (lane < 32) {
    __bf16 o[8];
#pragma unroll
    for (int j = 0; j < 8; ++j) o[j] = (__bf16)(ac[j] * inv);
    *(uint4*)(agg + (size_t)d * DIM + ln32 * 8) = *(uint4*)o;
  }
}

// ---------------------------------------------------------------------------
extern "C" void kernel_launch(void* const* d_in, const int* in_sizes, int n_in,
                              void* d_out, int out_size, void* d_ws, size_t ws_size,
                              hipStream_t stream)
{
  const float* h_in = (const float*)d_in[0];
  const int*   src  = (const int*)d_in[1];
  const int*   dst  = (const int*)d_in[2];
  const float* Wq   = (const float*)d_in[3];
  const float* Wk   = (const float*)d_in[4];
  const float* Wv   = (const float*)d_in[5];
  const float* Wo   = (const float*)d_in[6];
  const float* ln_g = (const float*)d_in[7];
  const float* ln_b = (const float*)d_in[8];
  const float* w1   = (const float*)d_in[9];
  const float* b1   = (const float*)d_in[10];
  const float* w2   = (const float*)d_in[11];
  const float* b2   = (const float*)d_in[12];
  float* out = (float*)d_out;

  // workspace layout (fp32-equivalent units)
  float*  ws   = (float*)d_ws;
  float*  hbuf = ws;                                  // NN*DIM fp32 (L1 LN out)
  float*  big  = hbuf + (size_t)NN * DIM;             // 15.36M floats
  __bf16* hbf  = (__bf16*)(big + (size_t)NN * 768);   // NN*DIM bf16
  __bf16* wbf  = hbf + (size_t)NN * DIM;              // 1.05M bf16
  int*    cnt      = (int*)(wbf + 1048576);           // NN
  int*    rowstart = cnt + NN;                        // NN+1
  int*    csrc     = rowstart + NN + 1;               // NE (src per CSR slot)

  unsigned char* qkvb = (unsigned char*)big;  // NN rows x 1024 B (q bf16|kv fp8)
  __bf16* ffnb = (__bf16*)big;                // NN*HUS bf16 (FFN hidden)

  __bf16* wqkvt = wbf;                       // 2 x [768][256] (kv permuted)
  __bf16* wot   = wqkvt + 2 * 768 * 256;     // 2 x [256][256]
  __bf16* w1t   = wot + 2 * 256 * 256;       // [1024][256]
  __bf16* w2t   = w1t + 1024 * 256;          // [256][1024]

  const dim3 blk(256);
  const int  g_node = (NN + 3) / 4;

  // prep: memset + mega-prep (transposes | h-init | hist) + scan + scatter
  hipMemsetAsync(cnt, 0, NN * sizeof(int), stream);
  prep_kernel<<<4774, blk, 0, stream>>>(Wq, Wk, Wv, Wo, w1, w2,
                                        wqkvt, wot, w1t, w2t,
                                        h_in, hbf, dst, cnt);
  scan_kernel<<<1, 1024, 0, stream>>>(cnt, rowstart);
  scatter_kernel<<<(NE + 255) / 256, blk, 0, stream>>>(
      src, dst, rowstart, cnt, csrc, NE);

  // XCD-swizzled grids: grid = (8, ceil(mtiles/8)*ntiles)
  const int mt128 = (NN + 127) / 128;     // 157
  const int mt64  = (NN + 63) / 64;       // 313
  const dim3 g_qkv(8, ((mt128 + 7) / 8) * 6);   // N=768:  6 n-tiles
  const dim3 g_ffn1(8, ((mt128 + 7) / 8) * 8);  // N=1024: 8 n-tiles
  const dim3 g_ffn2(8, ((mt64 + 7) / 8) * 2);   // N=256:  2 n-tiles, BM=64
  const int  g_woln = NN / 32;                  // 625 blocks (exact)

  for (int l = 0; l < NLAYER; ++l) {
    // fused q|kv projection -> q bf16 + kv fp8, row stride 1024 B
    gemm_bf16_t<0, 128><<<g_qkv, blk, 0, stream>>>(
        hbf, DIM, wqkvt + (size_t)l * 196608, DIM, qkvb, 512,
        nullptr, NN, 768, DIM, 0, 2, mt128, 6);

    // split-wave single-pass attention; agg -> bf16 into hbf
    node_attn<<<g_node, blk, 0, stream>>>(qkvb, rowstart, csrc, hbf);

    // fused Wo-GEMM + residual + LN -> hbf (bf16) [+ hbuf fp32 if needed]
    // layer 0: residual = h_in, fp32 out -> hbuf (layer-1 residual)
    // layer 1: residual = hbuf, fp32 out dead -> skipped
    gemm_wo_ln<<<g_woln, blk, 0, stream>>>(
        hbf, wot + (size_t)l * 65536,
        (l == 0) ? h_in : hbuf,
        (l == 0) ? hbuf : nullptr,
        hbf, ln_g + l * DIM, ln_b + l * DIM);
  }

  // FFN1: relu(h@w1+b1) -> bf16 hidden
  gemm_bf16_t<1, 128><<<g_ffn1, blk, 0, stream>>>(
      hbf, DIM, w1t, DIM, ffnb, HUS, b1, NN, HUS, DIM, 1, 1, mt128, 8);
  // FFN2: hidden @ w2 + b2 -> out (fp32)
  gemm_bf16_t<2, 64><<<g_ffn2, blk, 0, stream>>>(
      ffnb, HUS, w2t, HUS, out, DIM, b2, NN, DIM, HUS, 0, 0, mt64, 2);
}

// Round 9
// 300.916 us; speedup vs baseline: 1.0217x; 1.0217x over previous
//
#include <hip/hip_runtime.h>
#include <cstddef>

// Problem constants (from reference)
#define NN 20000      // nodes
#define NE 320000     // edges
#define DIM 256       // model dim
#define NHEAD 8
#define DHEAD 32      // DK == DV == 32
#define NLAYER 2
#define HUS 1024

typedef __bf16 bf16x8 __attribute__((ext_vector_type(8)));
typedef __bf16 bf16x4 __attribute__((ext_vector_type(4)));
typedef float  f32x4  __attribute__((ext_vector_type(4)));
typedef float  f32x2  __attribute__((ext_vector_type(2)));

// async global->LDS, 16B per lane; LDS dest must be wave-uniform base + lane*16
#define GLDS16(g, l) __builtin_amdgcn_global_load_lds(                        \
    (const __attribute__((address_space(1))) void*)(g),                       \
    (__attribute__((address_space(3))) void*)(l), 16, 0, 0)

// pack 4 fp32 -> 4 fp8 e4m3 (OCP on gfx950) in one uint
static __device__ inline unsigned pk_fp8x4(f32x4 x) {
  int v = 0;
  v = __builtin_amdgcn_cvt_pk_fp8_f32(x[0], x[1], v, false);
  v = __builtin_amdgcn_cvt_pk_fp8_f32(x[2], x[3], v, true);
  return (unsigned)v;
}

// ---------------------------------------------------------------------------
// bf16 MFMA GEMM: C[M,N] = A[M,K] @ Bt[N,K]^T  (A, Bt bf16 row-major)
// BM = BMT (128 or 64), BN=128, 256 threads = 4 waves 2x2.
// T3-minimum 2-phase pipeline (round-7 structure, best measured 304.9us):
// 32-K ping-pong buffers; per step: STAGE(next) -> ds_read+MFMA(cur) ->
// __syncthreads. 32 KB LDS -> 5 blocks/CU; cross-block TLP absorbs the
// drain (3-stage/48KB, depth-2-counted-vmcnt, B-in-VGPR all measured
// neutral-or-worse: rounds 3/6/8 — K-loop schedule is NOT the bottleneck).
// LDS swizzle (T2, 64B rows): (row, 16B-chunk) stored at chunk^((row>>1)&3);
// global source pre-swizzled (linear GLDS dest), read back with
// ko = (quad ^ ((col15>>1)&3))*8 -> conflict-free ds_read_b128.
// XCD swizzle: grid (8, ceil(mtiles/8)*ntiles); m = bx + 8*(by/ntiles).
// SCAT (this round): layer-0 instantiation carries the CSR scatter as
// extra blockIdx.y rows (by >= ylim) — latency-bound atomics co-resident
// with the compute-bound GEMM instead of a serial dispatch (m114 overlap).
// outmode: 0 = fp32, 1 = bf16, 2 = qkv-mixed (row = 1024B: 256 bf16 q at
// byte 0, 512 fp8 kv at byte 512; tiles bn<256 -> bf16, bn>=256 -> fp8).
// C/D layout: col = lane&15, row = quad*4 + reg.
// ---------------------------------------------------------------------------
template <int TAG, int BMT, bool SCAT>
__global__ __launch_bounds__(256) void gemm_bf16_t(
    const __bf16* __restrict__ A, int lda,
    const __bf16* __restrict__ Bt, int ldb,
    void* __restrict__ C, int ldc,
    const float* __restrict__ bias,
    int M, int N, int K, int relu, int outmode,
    int mtiles, int ntiles,
    const int* __restrict__ s_src, const int* __restrict__ s_dst,
    const int* __restrict__ s_rows, int* __restrict__ s_cur,
    int* __restrict__ s_csrc)
{
  constexpr int MT = BMT / 32;            // m-tiles per wave
  constexpr int BOFF = BMT * 32;          // Bs offset (elems) within buffer
  if (SCAT) {                             // ---- fused CSR scatter blocks ----
    const int ylim = ((mtiles + 7) >> 3) * ntiles;
    if ((int)blockIdx.y >= ylim) {
      int sid = blockIdx.x + 8 * (blockIdx.y - ylim);
      int e = sid * 256 + threadIdx.x;
      if (e < NE) {
        int d = s_dst[e];
        int pos = atomicAdd(&s_cur[d], 1);
        s_csrc[s_rows[d] + pos] = s_src[e];
      }
      return;
    }
  }
  const int mblk = blockIdx.x + 8 * (blockIdx.y / ntiles);
  const int nblk = blockIdx.y % ntiles;
  if (mblk >= mtiles) return;             // uniform early-out (idle pad blocks)
  __shared__ __align__(16) __bf16 smem[2][256 * 32];  // 32 KB total
  const int tid  = threadIdx.x;
  const int wave = tid >> 6;
  const int lane = tid & 63;
  const int bm = mblk * BMT;
  const int bn = nblk * 128;
  const int wm = (wave >> 1) * (BMT / 2);
  const int wn = (wave & 1) * 64;
  const int quad  = lane >> 4;
  const int col15 = lane & 15;

  // A staging per 32-K step: BMT*4 chunks of 16B; source chunk pre-swizzled
  const int swsrc = ((tid & 3) ^ ((tid >> 3) & 3)) * 8;   // elems
  const int ar1 = tid >> 2;
  const bool mok1 = (bm + ar1) < M;
  const __bf16* ag1 = A + (size_t)(bm + ar1) * lda + swsrc;
  const int ar2 = (tid + 256) >> 2;
  const bool mok2 = (BMT == 128) && ((bm + ar2) < M);
  const __bf16* ag2 = A + (size_t)(bm + ar2) * lda + swsrc; // (tid+256)>>3 ≡ tid>>3 (mod 4)

  // stage one 32-K step at global K-offset k into LDS buffer p
  auto stage_step = [&](int k, int p) {
    if (mok1) GLDS16(ag1 + k, &smem[p][tid * 8]);
    if (BMT == 128) {
      if (mok2) GLDS16(ag2 + k, &smem[p][(tid + 256) * 8]);
    }
#pragma unroll
    for (int i = 0; i < 2; ++i) {   // B: 512 chunks per step
      int c = tid + i * 256;
      GLDS16(Bt + (size_t)(bn + (c >> 2)) * ldb
                 + (((c & 3) ^ ((c >> 3) & 3)) * 8) + k,
             &smem[p][BOFF + c * 8]);
    }
  };

  f32x4 acc[MT][4];
#pragma unroll
  for (int i = 0; i < MT; ++i)
#pragma unroll
    for (int j = 0; j < 4; ++j) acc[i][j] = (f32x4){0.f, 0.f, 0.f, 0.f};

  const int nsteps = K >> 5;
  stage_step(0, 0);
  __syncthreads();
  int p = 0;
  const int ko = (quad ^ ((col15 >> 1) & 3)) * 8;  // swizzled chunk read
  for (int s = 0; s < nsteps; ++s) {
    if (s + 1 < nsteps) stage_step((s + 1) * 32, p ^ 1);  // prefetch next
    bf16x8 af[MT], bfr[4];
#pragma unroll
    for (int mt = 0; mt < MT; ++mt)
      af[mt] = *(const bf16x8*)(&smem[p][(wm + mt * 16 + col15) * 32 + ko]);
#pragma unroll
    for (int nt = 0; nt < 4; ++nt)
      bfr[nt] = *(const bf16x8*)(
          &smem[p][BOFF + (wn + nt * 16 + col15) * 32 + ko]);
#pragma unroll
    for (int mt = 0; mt < MT; ++mt)
#pragma unroll
      for (int nt = 0; nt < 4; ++nt)
        acc[mt][nt] = __builtin_amdgcn_mfma_f32_16x16x32_bf16(
            af[mt], bfr[nt], acc[mt][nt], 0, 0, 0);
    __syncthreads();   // drains prefetch (flew during MFMA) + read completion
    p ^= 1;
  }

  // ---- LDS-restaged epilogue ----
  float bv[4];
#pragma unroll
  for (int nt = 0; nt < 4; ++nt)
    bv[nt] = bias ? bias[bn + wn + nt * 16 + col15] : 0.f;

  float* stg = ((float*)&smem[0][0]) + wave * 2048;  // 8 KB/wave

#pragma unroll
  for (int mt = 0; mt < MT; ++mt) {
    __syncthreads();  // uniform; protects smem reuse across quarters
#pragma unroll
    for (int nt = 0; nt < 4; ++nt)
#pragma unroll
      for (int r = 0; r < 4; ++r) {
        float o = acc[mt][nt][r] + bv[nt];
        if (relu) o = fmaxf(o, 0.f);
        stg[(quad * 4 + r) * 68 + nt * 16 + col15] = o;
      }
    const int rbase = bm + wm + mt * 16;
    if (outmode == 0) {                       // fp32 out
      float* Cf = (float*)C;
#pragma unroll
      for (int it = 0; it < 4; ++it) {
        int t = it * 64 + lane;
        int row = t >> 4, cg = t & 15;
        int gr = rbase + row;
        if (gr < M) {
          f32x4 x = *(const f32x4*)(stg + row * 68 + cg * 4);
          *(f32x4*)(Cf + (size_t)gr * ldc + bn + wn + cg * 4) = x;
        }
      }
    } else if (outmode == 1 || bn < 256) {    // bf16 out (ldc in bf16 units)
      __bf16* Cb = (__bf16*)C;
#pragma unroll
      for (int it = 0; it < 2; ++it) {
        int t = it * 64 + lane;
        int row = t >> 3, cg = t & 7;
        int gr = rbase + row;
        if (gr < M) {
          f32x4 x = *(const f32x4*)(stg + row * 68 + cg * 8);
          f32x4 y = *(const f32x4*)(stg + row * 68 + cg * 8 + 4);
          __bf16 o8[8] = {(__bf16)x[0], (__bf16)x[1], (__bf16)x[2], (__bf16)x[3],
                          (__bf16)y[0], (__bf16)y[1], (__bf16)y[2], (__bf16)y[3]};
          *(uint4*)(Cb + (size_t)gr * ldc + bn + wn + cg * 8) = *(uint4*)o8;
        }
      }
    } else {                                   // fp8 kv region of qkv row
      unsigned char* C8 = (unsigned char*)C;
      int row = lane >> 2, cg = lane & 3;      // 16 rows x 4 groups of 16 cols
      int gr = rbase + row;
      if (gr < M) {
        uint4 o;
        o.x = pk_fp8x4(*(const f32x4*)(stg + row * 68 + cg * 16 + 0));
        o.y = pk_fp8x4(*(const f32x4*)(stg + row * 68 + cg * 16 + 4));
        o.z = pk_fp8x4(*(const f32x4*)(stg + row * 68 + cg * 16 + 8));
        o.w = pk_fp8x4(*(const f32x4*)(stg + row * 68 + cg * 16 + 12));
        *(uint4*)(C8 + (size_t)gr * 1024 + 512 + (bn - 256) + wn + cg * 16) = o;
      }
    }
  }
}

// ---------------------------------------------------------------------------
// Fused Wo-GEMM + residual + LayerNorm, LDS-restaged output.
// T2 chunk-swizzle + 2-phase prefetch pipeline (32-K steps).
// Residual source (hres, fp32) is decoupled from fp32 output (hout):
// layer 0 reads h_in directly (hbuf copy eliminated); layer 1 passes
// hout=nullptr (fp32 result is dead -> skip 20.5 MB of stores).
// ---------------------------------------------------------------------------
__global__ __launch_bounds__(256) void gemm_wo_ln(
    const __bf16* __restrict__ A,   // agg bf16 [M][256]
    const __bf16* __restrict__ Bt,  // wot [256][256]
    const float* __restrict__ hres, // fp32 residual in
    float* __restrict__ hout,       // fp32 LN out (may be null)
    __bf16* __restrict__ hb,        // bf16 LN out
    const float* __restrict__ g, const float* __restrict__ bb)
{
  __shared__ __align__(16) __bf16 smem[2][288 * 32];
  __shared__ float red_s[32][2], red_q[32][2];
  const int tid  = threadIdx.x;
  const int wave = tid >> 6;
  const int lane = tid & 63;
  const int quad  = lane >> 4;
  const int col15 = lane & 15;
  const int bm = blockIdx.x * 32;
  const int wm = (wave >> 1) * 16;
  const int wn = (wave & 1) * 128;
  const int ch = wave & 1;

  const int ac   = tid & 127;
  const int arow = ac >> 2;
  const int aoff = ((ac & 3) ^ ((ac >> 3) & 3)) * 8;   // pre-swizzled source
  const __bf16* agp = A + (size_t)(bm + arow) * 256 + aoff;

  // stage one 32-K step at global K-offset k into LDS buffer p:
  // A: 128 chunks (threads 0..127), B: 1024 chunks (4/thread)
  auto stage_step = [&](int k, int p) {
    if (tid < 128) GLDS16(agp + k, &smem[p][ac * 8]);
#pragma unroll
    for (int i = 0; i < 4; ++i) {
      int c = tid + i * 256;
      GLDS16(Bt + (size_t)(c >> 2) * 256
                 + (((c & 3) ^ ((c >> 3) & 3)) * 8) + k,
             &smem[p][1024 + c * 8]);
    }
  };

  f32x4 acc[8];
#pragma unroll
  for (int j = 0; j < 8; ++j) acc[j] = (f32x4){0.f, 0.f, 0.f, 0.f};

  stage_step(0, 0);
  __syncthreads();
  int p = 0;
  const int ko = (quad ^ ((col15 >> 1) & 3)) * 8;  // swizzled chunk read
  for (int s = 0; s < 8; ++s) {                    // 256/32 steps
    if (s + 1 < 8) stage_step((s + 1) * 32, p ^ 1);
    bf16x8 af = *(const bf16x8*)(&smem[p][(wm + col15) * 32 + ko]);
#pragma unroll
    for (int nt = 0; nt < 8; ++nt) {
      bf16x8 bfr = *(const bf16x8*)(
          &smem[p][1024 + (wn + nt * 16 + col15) * 32 + ko]);
      acc[nt] = __builtin_amdgcn_mfma_f32_16x16x32_bf16(af, bfr, acc[nt],
                                                        0, 0, 0);
    }
    __syncthreads();
    p ^= 1;
  }

#pragma unroll
  for (int r = 0; r < 4; ++r) {
    const int lr = wm + quad * 4 + r;
    const int gr = bm + lr;
    float s = 0.f, q = 0.f;
#pragma unroll
    for (int nt = 0; nt < 8; ++nt) {
      int gc = wn + nt * 16 + col15;
      float x = acc[nt][r] + hres[(size_t)gr * 256 + gc];
      acc[nt][r] = x;
      s += x; q += x * x;
    }
    s += __shfl_xor(s, 1); q += __shfl_xor(q, 1);
    s += __shfl_xor(s, 2); q += __shfl_xor(q, 2);
    s += __shfl_xor(s, 4); q += __shfl_xor(q, 4);
    s += __shfl_xor(s, 8); q += __shfl_xor(q, 8);
    if (col15 == 0) { red_s[lr][ch] = s; red_q[lr][ch] = q; }
  }
  __syncthreads();

  float* stg = (float*)&smem[0][0];
#pragma unroll
  for (int r = 0; r < 4; ++r) {
    const int lr = wm + quad * 4 + r;
    float s = red_s[lr][0] + red_s[lr][1];
    float q = red_q[lr][0] + red_q[lr][1];
    float mu  = s * (1.f / 256);
    float var = q * (1.f / 256) - mu * mu;
    float inv = rsqrtf(var + 1e-5f);
#pragma unroll
    for (int nt = 0; nt < 8; ++nt) {
      int gc = wn + nt * 16 + col15;
      stg[lr * 260 + gc] = (acc[nt][r] - mu) * inv * g[gc] + bb[gc];
    }
  }
  __syncthreads();

  if (hout) {
#pragma unroll
    for (int it = 0; it < 8; ++it) {
      int t = it * 256 + tid;
      int row = t >> 6, cg = t & 63;
      f32x4 x = *(const f32x4*)(stg + row * 260 + cg * 4);
      *(f32x4*)(hout + (size_t)(bm + row) * 256 + cg * 4) = x;
    }
  }
#pragma unroll
  for (int it = 0; it < 4; ++it) {
    int t = it * 256 + tid;
    int row = t >> 5, cg = t & 31;
    f32x4 x = *(const f32x4*)(stg + row * 260 + cg * 8);
    f32x4 y = *(const f32x4*)(stg + row * 260 + cg * 8 + 4);
    __bf16 o8[8] = {(__bf16)x[0], (__bf16)x[1], (__bf16)x[2], (__bf16)x[3],
                    (__bf16)y[0], (__bf16)y[1], (__bf16)y[2], (__bf16)y[3]};
    *(uint4*)(hb + (size_t)(bm + row) * 256 + cg * 8) = *(uint4*)o8;
  }
}

// ---------------------------------------------------------------------------
// PREP mega-kernel: transposes | h-init (bf16 only; fp32 copy eliminated —
// layer-1 residual reads h_in directly) | histogram.
// ---------------------------------------------------------------------------
__global__ __launch_bounds__(256) void prep_kernel(
    const float* __restrict__ Wq, const float* __restrict__ Wk,
    const float* __restrict__ Wv, const float* __restrict__ Wo,
    const float* __restrict__ w1, const float* __restrict__ w2,
    __bf16* __restrict__ wqkvt, __bf16* __restrict__ wot,
    __bf16* __restrict__ w1t, __bf16* __restrict__ w2t,
    const float* __restrict__ h_in,
    __bf16* __restrict__ hb,
    const int* __restrict__ dst, int* __restrict__ cnt)
{
  __shared__ float t[32][33];
  const int b = blockIdx.x;
  if (b >= 3524) {               // ---- histogram ----
    int e = (b - 3524) * 256 + threadIdx.x;
    if (e < NE) atomicAdd(&cnt[dst[e]], 1);
    return;
  }
  if (b >= 1024) {               // ---- h init (bf16 mirror only) ----
    int i = ((b - 1024) * 256 + threadIdx.x) * 8;
    if (i >= NN * DIM) return;
    float4 a = *(const float4*)(h_in + i);
    float4 c = *(const float4*)(h_in + i + 4);
    __bf16 o[8] = {(__bf16)a.x, (__bf16)a.y, (__bf16)a.z, (__bf16)a.w,
                   (__bf16)c.x, (__bf16)c.y, (__bf16)c.z, (__bf16)c.w};
    *(uint4*)(hb + i) = *(uint4*)o;
    return;
  }
  // ---- weight transposes ----
  const float* src;
  __bf16* dstp;
  int N, Kd, bk, bn, mode = 0;  // 0: identity, 1: k-perm, 2: v-perm
  if (b < 512) {
    int m = b >> 6, tt = b & 63;
    bk = (tt & 7) * 32; bn = (tt >> 3) * 32;
    N = 256; Kd = 256;
    int l = m & 1, w = m >> 1;  // w: 0=Wq 1=Wk 2=Wv 3=Wo
    const float* Ws[4] = {Wq, Wk, Wv, Wo};
    src = Ws[w] + (size_t)l * 65536;
    if (w == 3) dstp = wot + (size_t)l * 65536;
    else { dstp = wqkvt + (size_t)l * 196608; mode = (w == 0) ? 0 : w; }
  } else if (b < 768) {
    int tt = b - 512;
    bk = (tt & 7) * 32; bn = (tt >> 3) * 32;
    N = 1024; Kd = 256; src = w1; dstp = w1t;
  } else {
    int tt = b - 768;
    bk = (tt >> 3) * 32; bn = (tt & 7) * 32;
    N = 256; Kd = 1024; src = w2; dstp = w2t;
  }
  const int tx = threadIdx.x & 31, ty = threadIdx.x >> 5;
#pragma unroll
  for (int i = 0; i < 32; i += 8)
    t[ty + i][tx] = src[(size_t)(bk + ty + i) * N + bn + tx];
  __syncthreads();
#pragma unroll
  for (int i = 0; i < 32; i += 8) {
    int n = bn + ty + i;
    int r = (mode == 0) ? n
          : 256 + ((n >> 2) * 8) + (n & 3) + (mode == 2 ? 4 : 0);
    dstp[(size_t)r * Kd + bk + tx] = (__bf16)t[tx][ty + i];
  }
}

// ---------------------------------------------------------------------------
// CSR build: shfl-based scan (2 barriers). Scatter is fused into the
// layer-0 qkv dispatch (gemm_bf16_t<0,128,true>).
// Re-zeros cnt for cursor reuse; stores SRC id per CSR slot.
// ---------------------------------------------------------------------------
__global__ __launch_bounds__(1024) void scan_kernel(
    int* __restrict__ cnt, int* __restrict__ rowstart)
{
  __shared__ int wsum[16];
  const int t = threadIdx.x;
  const int lane = t & 63, w = t >> 6;
  const int CHUNK = (NN + 1023) / 1024;  // 20
  const int base = t * CHUNK;
  int loc[CHUNK];
  int s = 0;
#pragma unroll
  for (int i = 0; i < CHUNK; ++i) {
    int idx = base + i;
    loc[i] = (idx < NN) ? cnt[idx] : 0;
    s += loc[i];
  }
  // wave-inclusive scan of per-thread sums
  int ps = s;
#pragma unroll
  for (int off = 1; off < 64; off <<= 1) {
    int v = __shfl_up(ps, off);
    if (lane >= off) ps += v;
  }
  if (lane == 63) wsum[w] = ps;
  __syncthreads();
  if (t < 16) {
    int v = wsum[t];
    int pv = v;
#pragma unroll
    for (int off = 1; off < 16; off <<= 1) {
      int u = __shfl_up(pv, off);
      if (t >= off) pv += u;
    }
    if (t == 15) rowstart[NN] = pv;   // total
    wsum[t] = pv - v;                 // exclusive wave prefix
  }
  __syncthreads();
  int run = wsum[w] + (ps - s);       // exclusive prefix for this thread
#pragma unroll
  for (int i = 0; i < CHUNK; ++i) {
    int idx = base + i;
    if (idx < NN) {
      rowstart[idx] = run;
      run += loc[i];
      cnt[idx] = 0;
    }
  }
}

// ---------------------------------------------------------------------------
// Fused per-node attention, split-wave + depth-4 pipeline: one wave per dst
// node, two 32-lane halves each processing alternate edges with FOUR gathers
// in flight (p0..p3) -> 8 outstanding 512B gathers per wave (latency-bound
// regime: throughput ~ outstanding/latency).
// qkv rows 1024 B: q bf16 (bytes 0..511), kv fp8 e4m3 (512..1023).
// ---------------------------------------------------------------------------
__global__ __launch_bounds__(256) void node_attn(
    const unsigned char* __restrict__ qkv,
    const int* __restrict__ rowstart, const int* __restrict__ csrc,
    __bf16* __restrict__ agg)
{
  const int wave = threadIdx.x >> 6;
  const int lane = threadIdx.x & 63;
  const int hw   = lane >> 5;
  const int ln32 = lane & 31;
  const int d = blockIdx.x * 4 + wave;
  if (d >= NN) return;
  const int beg = rowstart[d], end = rowstart[d + 1];

  float qf[8];
  {
    bf16x8 q8 = *(const bf16x8*)(qkv + (size_t)d * 1024 + ln32 * 16);
#pragma unroll
    for (int j = 0; j < 8; ++j) qf[j] = (float)q8[j];
  }
  const float scale = 0.17677669529663687f;  // 1/sqrt(32)
  float z = 0.f;
  float ac[8];
#pragma unroll
  for (int j = 0; j < 8; ++j) ac[j] = 0.f;

  for (int c = beg; c < end; c += 64) {
    const int n = min(64, end - c);
    const int myi = c + lane;
    const int s_l = (myi < end) ? csrc[myi] : 0;   // coalesced batch load

    uint4 p0 = make_uint4(0u, 0u, 0u, 0u);
    uint4 p1 = make_uint4(0u, 0u, 0u, 0u);
    uint4 p2 = make_uint4(0u, 0u, 0u, 0u);
    uint4 p3 = make_uint4(0u, 0u, 0u, 0u);
    if (hw < n) {
      int s = __shfl(s_l, hw);
      p0 = *(const uint4*)(qkv + (size_t)s * 1024 + 512 + ln32 * 16);
    }
    if (hw + 2 < n) {
      int s = __shfl(s_l, hw + 2);
      p1 = *(const uint4*)(qkv + (size_t)s * 1024 + 512 + ln32 * 16);
    }
    if (hw + 4 < n) {
      int s = __shfl(s_l, hw + 4);
      p2 = *(const uint4*)(qkv + (size_t)s * 1024 + 512 + ln32 * 16);
    }
    if (hw + 6 < n) {
      int s = __shfl(s_l, hw + 6);
      p3 = *(const uint4*)(qkv + (size_t)s * 1024 + 512 + ln32 * 16);
    }
    for (int i = hw; i < n; i += 2) {
      uint4 kv = p0;
      p0 = p1; p1 = p2; p2 = p3;           // compile-time register shift
      if (i + 8 < n) {                     // refill the 4-deep pipe
        int sn = __shfl(s_l, i + 8);
        p3 = *(const uint4*)(qkv + (size_t)sn * 1024 + 512 + ln32 * 16);
      }
      f32x2 k01 = __builtin_amdgcn_cvt_pk_f32_fp8(kv.x, false);
      f32x2 k23 = __builtin_amdgcn_cvt_pk_f32_fp8(kv.x, true);
      f32x2 k45 = __builtin_amdgcn_cvt_pk_f32_fp8(kv.z, false);
      f32x2 k67 = __builtin_amdgcn_cvt_pk_f32_fp8(kv.z, true);
      float p = qf[0] * k01[0] + qf[1] * k01[1] + qf[2] * k23[0] +
                qf[3] * k23[1] + qf[4] * k45[0] + qf[5] * k45[1] +
                qf[6] * k67[0] + qf[7] * k67[1];
      p += __shfl_xor(p, 1);
      p += __shfl_xor(p, 2);
      float a = __expf(p * scale);
      z += a;
      f32x2 v01 = __builtin_amdgcn_cvt_pk_f32_fp8(kv.y, false);
      f32x2 v23 = __builtin_amdgcn_cvt_pk_f32_fp8(kv.y, true);
      f32x2 v45 = __builtin_amdgcn_cvt_pk_f32_fp8(kv.w, false);
      f32x2 v67 = __builtin_amdgcn_cvt_pk_f32_fp8(kv.w, true);
      ac[0] += a * v01[0]; ac[1] += a * v01[1];
      ac[2] += a * v23[0]; ac[3] += a * v23[1];
      ac[4] += a * v45[0]; ac[5] += a * v45[1];
      ac[6] += a * v67[0]; ac[7] += a * v67[1];
    }
  }
  // combine halves
  z += __shfl_xor(z, 32);
#pragma unroll
  for (int j = 0; j < 8; ++j) ac[j] += __shfl_xor(ac[j], 32);
  const float inv = 1.f / (z + 1e-9f);
  if (lane < 32) {
    __bf16 o[8];
#pragma unroll
    for (int j = 0; j < 8; ++j) o[j] = (__bf16)(ac[j] * inv);
    *(uint4*)(agg + (size_t)d * DIM + ln32 * 8) = *(uint4*)o;
  }
}

// ---------------------------------------------------------------------------
extern "C" void kernel_launch(void* const* d_in, const int* in_sizes, int n_in,
                              void* d_out, int out_size, void* d_ws, size_t ws_size,
                              hipStream_t stream)
{
  const float* h_in = (const float*)d_in[0];
  const int*   src  = (const int*)d_in[1];
  const int*   dst  = (const int*)d_in[2];
  const float* Wq   = (const float*)d_in[3];
  const float* Wk   = (const float*)d_in[4];
  const float* Wv   = (const float*)d_in[5];
  const float* Wo   = (const float*)d_in[6];
  const float* ln_g = (const float*)d_in[7];
  const float* ln_b = (const float*)d_in[8];
  const float* w1   = (const float*)d_in[9];
  const float* b1   = (const float*)d_in[10];
  const float* w2   = (const float*)d_in[11];
  const float* b2   = (const float*)d_in[12];
  float* out = (float*)d_out;

  // workspace layout (fp32-equivalent units)
  float*  ws   = (float*)d_ws;
  float*  hbuf = ws;                                  // NN*DIM fp32 (L1 LN out)
  float*  big  = hbuf + (size_t)NN * DIM;             // 15.36M floats
  __bf16* hbf  = (__bf16*)(big + (size_t)NN * 768);   // NN*DIM bf16
  __bf16* wbf  = hbf + (size_t)NN * DIM;              // 1.05M bf16
  int*    cnt      = (int*)(wbf + 1048576);           // NN
  int*    rowstart = cnt + NN;                        // NN+1
  int*    csrc     = rowstart + NN + 1;               // NE (src per CSR slot)

  unsigned char* qkvb = (unsigned char*)big;  // NN rows x 1024 B (q bf16|kv fp8)
  __bf16* ffnb = (__bf16*)big;                // NN*HUS bf16 (FFN hidden)

  __bf16* wqkvt = wbf;                       // 2 x [768][256] (kv permuted)
  __bf16* wot   = wqkvt + 2 * 768 * 256;     // 2 x [256][256]
  __bf16* w1t   = wot + 2 * 256 * 256;       // [1024][256]
  __bf16* w2t   = w1t + 1024 * 256;          // [256][1024]

  const dim3 blk(256);
  const int  g_node = (NN + 3) / 4;

  // prep: memset + mega-prep (transposes | h-init | hist) + scan
  hipMemsetAsync(cnt, 0, NN * sizeof(int), stream);
  prep_kernel<<<4774, blk, 0, stream>>>(Wq, Wk, Wv, Wo, w1, w2,
                                        wqkvt, wot, w1t, w2t,
                                        h_in, hbf, dst, cnt);
  scan_kernel<<<1, 1024, 0, stream>>>(cnt, rowstart);

  // XCD-swizzled grids: grid = (8, ceil(mtiles/8)*ntiles)
  const int mt128 = (NN + 127) / 128;     // 157
  const int mt64  = (NN + 63) / 64;       // 313
  const int y_qkv = ((mt128 + 7) / 8) * 6;      // 120 (N=768: 6 n-tiles)
  const int y_sct = (NE / 256 + 7) / 8 + 1;     // 157 rows -> 1256 scatter blocks
  const dim3 g_qkv0(8, y_qkv + y_sct);          // layer-0: qkv + fused scatter
  const dim3 g_qkv(8, y_qkv);
  const dim3 g_ffn1(8, ((mt128 + 7) / 8) * 8);  // N=1024: 8 n-tiles
  const dim3 g_ffn2(8, ((mt64 + 7) / 8) * 2);   // N=256:  2 n-tiles, BM=64
  const int  g_woln = NN / 32;                  // 625 blocks (exact)

  for (int l = 0; l < NLAYER; ++l) {
    // fused q|kv projection -> q bf16 + kv fp8, row stride 1024 B
    // layer 0 additionally carries the CSR scatter (extra y rows)
    if (l == 0) {
      gemm_bf16_t<0, 128, true><<<g_qkv0, blk, 0, stream>>>(
          hbf, DIM, wqkvt, DIM, qkvb, 512,
          nullptr, NN, 768, DIM, 0, 2, mt128, 6,
          src, dst, rowstart, cnt, csrc);
    } else {
      gemm_bf16_t<0, 128, false><<<g_qkv, blk, 0, stream>>>(
          hbf, DIM, wqkvt + (size_t)l * 196608, DIM, qkvb, 512,
          nullptr, NN, 768, DIM, 0, 2, mt128, 6,
          nullptr, nullptr, nullptr, nullptr, nullptr);
    }

    // split-wave single-pass attention; agg -> bf16 into hbf
    node_attn<<<g_node, blk, 0, stream>>>(qkvb, rowstart, csrc, hbf);

    // fused Wo-GEMM + residual + LN -> hbf (bf16) [+ hbuf fp32 if needed]
    // layer 0: residual = h_in, fp32 out -> hbuf (layer-1 residual)
    // layer 1: residual = hbuf, fp32 out dead -> skipped
    gemm_wo_ln<<<g_woln, blk, 0, stream>>>(
        hbf, wot + (size_t)l * 65536,
        (l == 0) ? h_in : hbuf,
        (l == 0) ? hbuf : nullptr,
        hbf, ln_g + l * DIM, ln_b + l * DIM);
  }

  // FFN1: relu(h@w1+b1) -> bf16 hidden
  gemm_bf16_t<1, 128, false><<<g_ffn1, blk, 0, stream>>>(
      hbf, DIM, w1t, DIM, ffnb, HUS, b1, NN, HUS, DIM, 1, 1, mt128, 8,
      nullptr, nullptr, nullptr, nullptr, nullptr);
  // FFN2: hidden @ w2 + b2 -> out (fp32)
  gemm_bf16_t<2, 64, false><<<g_ffn2, blk, 0, stream>>>(
      ffnb, HUS, w2t, HUS, out, DIM, b2, NN, DIM, HUS, 0, 0, mt64, 2,
      nullptr, nullptr, nullptr, nullptr, nullptr);
}